// Round 4
// baseline (11361.726 us; speedup 1.0000x reference)
//
#include <hip/hip_runtime.h>
#include <hip/hip_bf16.h>
#include <math.h>

// Problem constants
#define NB    32    // batch
#define NSEED 128
#define NTT   512   // total timesteps (128 seed + 384 gen)
#define NIN   171
#define NINP  192   // padded input dim (6 k-tiles of 32)
#define NH    1024
#define NG    4096  // 4*H
#define NOUT  171
#define NOUTP 176   // padded to 11 n-tiles of 16
#define NWG   256

typedef unsigned short u16;
typedef unsigned int u32;
typedef __attribute__((ext_vector_type(8))) short bf16x8;
typedef __attribute__((ext_vector_type(4))) float f32x4;

__device__ __host__ inline u16 f2bf(float x) {
  union { float f; unsigned u; } v; v.f = x;
  unsigned r = v.u + 0x7FFFu + ((v.u >> 16) & 1u);
  return (u16)(r >> 16);
}

// ---------------------------------------------------------------------------
// Packing kernels (unchanged)
// ---------------------------------------------------------------------------
__global__ void pack_mat(const float* __restrict__ src, u16* __restrict__ dst, int ktiles) {
  int id = blockIdx.x * 256 + threadIdx.x;
  int total = ktiles * 256 * 64;
  if (id >= total) return;
  int lane = id & 63;
  int nt = (id >> 6) & 255;
  int kt = id >> 14;
  int c = lane & 15, q = lane >> 4;
  int r = (c & 3) * 1024 + nt * 4 + (c >> 2);
  int K = ktiles * 32;
  const float* s = src + (size_t)r * K + kt * 32 + q * 8;
  __attribute__((aligned(16))) u16 o[8];
#pragma unroll
  for (int j = 0; j < 8; ++j) o[j] = f2bf(s[j]);
  *(bf16x8*)(dst + (size_t)id * 8) = *(const bf16x8*)o;
}

__global__ void pack_wih1(const float* __restrict__ src, u16* __restrict__ dst) {
  int id = blockIdx.x * 256 + threadIdx.x;
  if (id >= 6 * 256 * 64) return;
  int lane = id & 63;
  int nt = (id >> 6) & 255;
  int kt = id >> 14;
  int c = lane & 15, q = lane >> 4;
  int r = (c & 3) * 1024 + nt * 4 + (c >> 2);
  int k0 = kt * 32 + q * 8;
  __attribute__((aligned(16))) u16 o[8];
#pragma unroll
  for (int j = 0; j < 8; ++j) {
    int k = k0 + j;
    o[j] = (k < NIN) ? f2bf(src[(size_t)r * NIN + k]) : (u16)0;
  }
  *(bf16x8*)(dst + (size_t)id * 8) = *(const bf16x8*)o;
}

__global__ void pack_wdec(const float* __restrict__ src, u16* __restrict__ dst) {
  int id = blockIdx.x * 256 + threadIdx.x;
  if (id >= 32 * 11 * 64) return;
  int lane = id & 63;
  int nt = (id >> 6) % 11;
  int kt = (id >> 6) / 11;
  int c = lane & 15, q = lane >> 4;
  int r = nt * 16 + c;  // output column
  int k0 = kt * 32 + q * 8;
  __attribute__((aligned(16))) u16 o[8];
#pragma unroll
  for (int j = 0; j < 8; ++j) {
    o[j] = (r < NOUT) ? f2bf(src[(size_t)r * NH + k0 + j]) : (u16)0;
  }
  *(bf16x8*)(dst + (size_t)id * 8) = *(const bf16x8*)o;
}

__global__ void pack_seed(const float* __restrict__ src, u16* __restrict__ dst) {
  int id = blockIdx.x * 256 + threadIdx.x;
  if (id >= NSEED * NB * NINP) return;
  int kp = id % NINP;
  int b = (id / NINP) % NB;
  int t = id / (NINP * NB);
  float v = (kp < NIN) ? src[((size_t)b * NSEED + t) * NIN + kp] : 0.f;
  dst[id] = f2bf(v);
}

__global__ void wfuse_kernel(const float* __restrict__ wih1, const float* __restrict__ wdec,
                             float* __restrict__ tmp) {
  int n = blockIdx.x;
  int k = blockIdx.y * 256 + threadIdx.x;
  const float* wr = wih1 + (size_t)n * NIN;
  float s = 0.f;
  for (int i = 0; i < NIN; ++i) s += wr[i] * wdec[(size_t)i * NH + k];
  tmp[(size_t)n * NH + k] = s;
}

__global__ void prep_bias(const float* bih1, const float* bhh1, const float* bih2, const float* bhh2,
                          const float* bih3, const float* bhh3, const float* __restrict__ wih1,
                          const float* __restrict__ bdec_in,
                          float* b1s, float* b1g, float* b2, float* b3, float* bdecp,
                          int* __restrict__ cnt) {
  int n = blockIdx.x * 256 + threadIdx.x;
  if (n >= NG) return;
  if (n == 0) cnt[0] = 0;          // zero the epoch counter (ws is poisoned)
  int wgi = n >> 4, c = n & 15;
  int r = (c & 3) * 1024 + wgi * 4 + (c >> 2);
  float v1 = bih1[r] + bhh1[r];
  b1s[n] = v1;
  float bf = 0.f;
  for (int i = 0; i < NIN; ++i) bf += wih1[(size_t)r * NIN + i] * bdec_in[i];
  b1g[n] = v1 + bf;
  b2[n] = bih2[r] + bhh2[r];
  b3[n] = bih3[r] + bhh3[r];
  if (n < NOUTP) bdecp[n] = (n < NOUT) ? bdec_in[n] : 0.f;
}

// ---------------------------------------------------------------------------
// Coherent (sc0 sc1) batched A-fragment load: 16x dwordx4 from the two row
// tiles, single trailing vmcnt(0). Bypasses stale L1/L2 -> reads the agent
// coherent point. Bases pre-offset by (m*rs + q*8 + wv*32).
// ---------------------------------------------------------------------------
__device__ __forceinline__ void load16_sc1(bf16x8 (&a0)[8], bf16x8 (&a1)[8],
                                           const u16* b0, const u16* b1) {
  asm volatile(
      "global_load_dwordx4 %0, %16, off sc0 sc1\n\t"
      "global_load_dwordx4 %8, %17, off sc0 sc1\n\t"
      "global_load_dwordx4 %1, %16, off offset:256 sc0 sc1\n\t"
      "global_load_dwordx4 %9, %17, off offset:256 sc0 sc1\n\t"
      "global_load_dwordx4 %2, %16, off offset:512 sc0 sc1\n\t"
      "global_load_dwordx4 %10, %17, off offset:512 sc0 sc1\n\t"
      "global_load_dwordx4 %3, %16, off offset:768 sc0 sc1\n\t"
      "global_load_dwordx4 %11, %17, off offset:768 sc0 sc1\n\t"
      "global_load_dwordx4 %4, %16, off offset:1024 sc0 sc1\n\t"
      "global_load_dwordx4 %12, %17, off offset:1024 sc0 sc1\n\t"
      "global_load_dwordx4 %5, %16, off offset:1280 sc0 sc1\n\t"
      "global_load_dwordx4 %13, %17, off offset:1280 sc0 sc1\n\t"
      "global_load_dwordx4 %6, %16, off offset:1536 sc0 sc1\n\t"
      "global_load_dwordx4 %14, %17, off offset:1536 sc0 sc1\n\t"
      "global_load_dwordx4 %7, %16, off offset:1792 sc0 sc1\n\t"
      "global_load_dwordx4 %15, %17, off offset:1792 sc0 sc1\n\t"
      "s_waitcnt vmcnt(0)"
      : "=&v"(a0[0]), "=&v"(a0[1]), "=&v"(a0[2]), "=&v"(a0[3]),
        "=&v"(a0[4]), "=&v"(a0[5]), "=&v"(a0[6]), "=&v"(a0[7]),
        "=&v"(a1[0]), "=&v"(a1[1]), "=&v"(a1[2]), "=&v"(a1[3]),
        "=&v"(a1[4]), "=&v"(a1[5]), "=&v"(a1[6]), "=&v"(a1[7])
      : "v"(b0), "v"(b1)
      : "memory");
}

#define MFMA_BF16 __builtin_amdgcn_mfma_f32_16x16x32_bf16

// K=1024 matmul, B from LDS (fresh-x, post-barrier path). x read coherently.
__device__ __forceinline__ void mm32_lds(f32x4& d0, f32x4& d1, const u16* wl,
                                         const u16* x, int wv, int lane) {
  int m = lane & 15, q = lane >> 4;
  const u16* xa = x + m * NH + q * 8 + wv * 32;
  const u16* xb = xa + 16 * NH;
  bf16x8 a0[8], a1[8];
  load16_sc1(a0, a1, xa, xb);
  const u16* wb = wl + lane * 8;
#pragma unroll
  for (int i = 0; i < 8; ++i) {
    bf16x8 w = *(const bf16x8*)(wb + (size_t)(wv + 4 * i) * 512);
    d0 = MFMA_BF16(a0[i], w, d0, 0, 0, 0);
    d1 = MFMA_BF16(a1[i], w, d1, 0, 0, 0);
  }
}

// K=1024 matmul, B from global (L2-resident weights), x read coherently.
__device__ __forceinline__ void mm32_glb(f32x4& d0, f32x4& d1, const u16* wgb,
                                         const u16* x, int wv, int lane) {
  int m = lane & 15, q = lane >> 4;
  const u16* xa = x + m * NH + q * 8 + wv * 32;
  const u16* xb = xa + 16 * NH;
  const u16* wb = wgb + lane * 8;
  bf16x8 w[8];
#pragma unroll
  for (int i = 0; i < 8; ++i) w[i] = *(const bf16x8*)(wb + (size_t)(wv + 4 * i) * 131072);
  bf16x8 a0[8], a1[8];
  load16_sc1(a0, a1, xa, xb);   // trailing vmcnt(0) also covers the w prefetch
#pragma unroll
  for (int i = 0; i < 8; ++i) {
    d0 = MFMA_BF16(a0[i], w[i], d0, 0, 0, 0);
    d1 = MFMA_BF16(a1[i], w[i], d1, 0, 0, 0);
  }
}

// K=192 (6 ktiles) seed-phase Wih1 path: both operands immutable -> cached.
__device__ __forceinline__ void mm6_glb(f32x4& d0, f32x4& d1, const u16* __restrict__ wbase,
                                        const u16* __restrict__ x, int wv, int lane) {
  int m = lane & 15, q = lane >> 4;
  const u16* xa = x + m * NINP + q * 8;
  const u16* xb = xa + 16 * NINP;
  const u16* wb = wbase + lane * 8;
#pragma unroll
  for (int i = 0; i < 2; ++i) {
    int kt = wv + 4 * i;
    if (kt >= 6) break;
    bf16x8 w = *(const bf16x8*)(wb + (size_t)kt * 131072);
    bf16x8 a0 = *(const bf16x8*)(xa + kt * 32);
    bf16x8 a1 = *(const bf16x8*)(xb + kt * 32);
    d0 = MFMA_BF16(a0, w, d0, 0, 0, 0);
    d1 = MFMA_BF16(a1, w, d1, 0, 0, 0);
  }
}

// ---------------------------------------------------------------------------
// Main persistent kernel. 256 WGs x 256 threads, 1 WG/CU.
// Grid sync = single monotone epoch counter:
//   signal: one relaxed agent fetch_add(cnt,1) per WG per stage
//   wait:   lane 0 of each wave polls cnt >= 256*ep (one dword, one line)
// No cache-maintenance ops anywhere in the steady state.
// ---------------------------------------------------------------------------
__global__ __launch_bounds__(256, 1) void lstm_main(
    const u16* __restrict__ whh1, const u16* __restrict__ whh2, const u16* __restrict__ whh3,
    const u16* __restrict__ wih2, const u16* __restrict__ wih3,
    const u16* __restrict__ wfuse, const u16* __restrict__ wih1,
    const u16* __restrict__ seedp,
    u16* __restrict__ h1b, u16* __restrict__ h2b, u16* __restrict__ h3h,
    const float* __restrict__ b1s, const float* __restrict__ b1g,
    const float* __restrict__ b2, const float* __restrict__ b3,
    int* __restrict__ cnt)
{
  __shared__ u16  wlds[3 * 16384];     // 96 KB: wih2 | wih3 | wfuse slices
  __shared__ float red[4][64][8];      // 4-wave split-K reduction (8 KB)
  __shared__ float gbuf[32][16];       // gates (b, packed col)
  __shared__ float cst[3][32][4];      // cell state: layer, batch, local j

  int wg = blockIdx.x;
  int tid = threadIdx.x;
  int wv = tid >> 6, lane = tid & 63;

  // ---- stage phase-B weight slices into LDS (one time) ----
  {
    const u16* srcs[3] = { wih2 + (size_t)wg * 512, wih3 + (size_t)wg * 512,
                           wfuse + (size_t)wg * 512 };
#pragma unroll
    for (int m = 0; m < 3; ++m) {
      for (int i = tid; i < 2048; i += 256) {          // 32 kt * 64 lanes
        int kt = i >> 6, ln = i & 63;
        *(bf16x8*)&wlds[m * 16384 + (kt * 64 + ln) * 8] =
            *(const bf16x8*)(srcs[m] + ((size_t)kt * 16384 + ln) * 8);
      }
    }
    float* cp = &cst[0][0][0];
    for (int i = tid; i < 3 * 32 * 4; i += 256) cp[i] = 0.f;
  }
  __syncthreads();

  // per-thread bias preload (epilogue uses c = tid & 15)
  int c0 = tid & 15;
  float bv_s  = b1s[wg * 16 + c0];
  float bv_g  = b1g[wg * 16 + c0];
  float bv_2  = b2 [wg * 16 + c0];
  float bv_3  = b3 [wg * 16 + c0];

  const u16* whhg[3] = { whh1 + (size_t)wg * 512, whh2 + (size_t)wg * 512,
                         whh3 + (size_t)wg * 512 };
  const u16* wih1g = wih1 + (size_t)wg * 512;

  int ep = 0;  // completed stages
  for (int t = 0; t < NTT; ++t) {
    int par = t & 1, parp = par ^ 1;
    for (int l = 0; l < 3; ++l) {
      f32x4 d0 = {0.f, 0.f, 0.f, 0.f}, d1 = {0.f, 0.f, 0.f, 0.f};
      bool isseed = (t < NSEED);

      // ---- pre-barrier work (inputs >= 3 stages old; h via coherent loads) ----
      if (l == 0 && isseed)
        mm6_glb(d0, d1, wih1g, seedp + (size_t)t * NB * NINP, wv, lane);
      if (t > 0) {            // recurrent term h_l[t-1] @ Whh_l^T
        const u16* hs = (l == 0) ? h1b + (size_t)parp * NB * NH
                     : (l == 1) ? h2b + (size_t)parp * NB * NH
                                : h3h + (size_t)(t - 1) * NB * NH;
        mm32_glb(d0, d1, whhg[l], hs, wv, lane);
      }

      // ---- epoch-counter wait (per-wave lane-0 poll; skip: seed l==0) ----
      bool skipwait = (l == 0 && isseed);
      if (ep > 0 && !skipwait) {
        int target = ep * NWG;
        if (lane == 0) {
          while (__hip_atomic_load(cnt, __ATOMIC_RELAXED, __HIP_MEMORY_SCOPE_AGENT) < target)
            __builtin_amdgcn_s_sleep(2);
        }
        // lanes reconverge here; whole wave was held while lane 0 spun
      }

      // ---- post-barrier: fresh input term (B from LDS, x coherent) ----
      if (l == 0) {
        if (!isseed)
          mm32_lds(d0, d1, &wlds[2 * 16384], h3h + (size_t)(t - 1) * NB * NH, wv, lane);
      } else {
        const u16* xs = (l == 1) ? h1b + (size_t)par * NB * NH
                                 : h2b + (size_t)par * NB * NH;
        mm32_lds(d0, d1, &wlds[(l - 1) * 16384], xs, wv, lane);
      }

      // ---- reduce the 4 waves' split-K partials via LDS ----
#pragma unroll
      for (int r = 0; r < 4; ++r) { red[wv][lane][r] = d0[r]; red[wv][lane][4 + r] = d1[r]; }
      __syncthreads();
      {
        int c = tid & 15, brow = tid >> 4;   // brow 0..15
        float bv = (l == 0) ? (isseed ? bv_s : bv_g) : (l == 1) ? bv_2 : bv_3;
        int srcl = ((brow >> 2) << 4) | c;   // D-frag: col=lane&15, row=(lane>>4)*4+reg
#pragma unroll
        for (int mt = 0; mt < 2; ++mt) {
          int b = brow + mt * 16;
          int idx = mt * 4 + (brow & 3);
          gbuf[b][c] = red[0][srcl][idx] + red[1][srcl][idx] +
                       red[2][srcl][idx] + red[3][srcl][idx] + bv;
        }
      }
      __syncthreads();

      // ---- pointwise LSTM cell; h exchange via relaxed agent u32 stores ----
      if (tid < 128) {
        int b = tid & 31, jl = tid >> 5;
        float gi = gbuf[b][jl * 4 + 0], gf = gbuf[b][jl * 4 + 1];
        float gg = gbuf[b][jl * 4 + 2], go = gbuf[b][jl * 4 + 3];
        float si = 1.f / (1.f + expf(-gi));
        float sf = 1.f / (1.f + expf(-gf));
        float so = 1.f / (1.f + expf(-go));
        float cn = sf * cst[l][b][jl] + si * tanhf(gg);
        cst[l][b][jl] = cn;
        float hn = so * tanhf(cn);
        unsigned hv = (unsigned)f2bf(hn);
        // pair (jl even, jl odd) lives at lane ^ 32 within the same wave
        unsigned other = (unsigned)__shfl_xor((int)hv, 32, 64);
        if (lane < 32) {
          unsigned val = hv | (other << 16);
          int w01 = tid >> 6;  // 0 -> cols (0,1), 1 -> cols (2,3)
          u16* hdst = (l == 0) ? h1b + (size_t)par * NB * NH
                    : (l == 1) ? h2b + (size_t)par * NB * NH
                               : h3h + (size_t)t * NB * NH;
          u32* hp = (u32*)hdst + (size_t)b * 512 + wg * 2 + w01;
          __hip_atomic_store(hp, val, __ATOMIC_RELAXED, __HIP_MEMORY_SCOPE_AGENT);
        }
      }

      // ---- signal stage completion (syncthreads drained vmcnt first) ----
      __syncthreads();
      ++ep;
      if (tid == 0)
        __hip_atomic_fetch_add(cnt, 1, __ATOMIC_RELAXED, __HIP_MEMORY_SCOPE_AGENT);
    }
  }
}

// ---------------------------------------------------------------------------
// Batched decoder: out[b][t][o] = h3[t] @ Wdec^T + bdec for all 512 steps.
// ---------------------------------------------------------------------------
__global__ __launch_bounds__(256) void dec_kernel(
    const u16* __restrict__ h3h, const u16* __restrict__ wdec,
    const float* __restrict__ bdecp, float* __restrict__ out)
{
  int task = blockIdx.x * 4 + (threadIdx.x >> 6);
  int lane = threadIdx.x & 63;
  int nt = task % 11, rt = task / 11;
  if (rt >= NTT) return;
  int m = lane & 15, q = lane >> 4;
  const u16* xa = h3h + ((size_t)rt * 32 + m) * NH + q * 8;
  const u16* xb = xa + (size_t)16 * NH;
  f32x4 d0 = {0.f, 0.f, 0.f, 0.f}, d1 = {0.f, 0.f, 0.f, 0.f};
  for (int kt = 0; kt < 32; ++kt) {
    bf16x8 bf = *(const bf16x8*)(wdec + ((size_t)(kt * 11 + nt) * 64 + lane) * 8);
    bf16x8 a0 = *(const bf16x8*)(xa + kt * 32);
    bf16x8 a1 = *(const bf16x8*)(xb + kt * 32);
    d0 = MFMA_BF16(a0, bf, d0, 0, 0, 0);
    d1 = MFMA_BF16(a1, bf, d1, 0, 0, 0);
  }
  int o = nt * 16 + m;
  if (o >= NOUT) return;
  float bv = bdecp[o];
#pragma unroll
  for (int reg = 0; reg < 4; ++reg) {
    int row0 = rt * 32 + q * 4 + reg;          // row = t*32 + b
    out[(((size_t)(row0 & 31)) * NTT + (row0 >> 5)) * NOUT + o] = d0[reg] + bv;
    int row1 = row0 + 16;
    out[(((size_t)(row1 & 31)) * NTT + (row1 >> 5)) * NOUT + o] = d1[reg] + bv;
  }
}

// ---------------------------------------------------------------------------
extern "C" void kernel_launch(void* const* d_in, const int* in_sizes, int n_in,
                              void* d_out, int out_size, void* d_ws, size_t ws_size,
                              hipStream_t stream) {
  const float* seed = (const float*)d_in[0];
  const float* Wih1 = (const float*)d_in[1];
  const float* Whh1 = (const float*)d_in[2];
  const float* bih1 = (const float*)d_in[3];
  const float* bhh1 = (const float*)d_in[4];
  const float* Wih2 = (const float*)d_in[5];
  const float* Whh2 = (const float*)d_in[6];
  const float* bih2 = (const float*)d_in[7];
  const float* bhh2 = (const float*)d_in[8];
  const float* Wih3 = (const float*)d_in[9];
  const float* Whh3 = (const float*)d_in[10];
  const float* bih3 = (const float*)d_in[11];
  const float* bhh3 = (const float*)d_in[12];
  const float* Wdec = (const float*)d_in[13];
  const float* bdec = (const float*)d_in[14];

  char* ws = (char*)d_ws;
  size_t off = 0;
  auto alloc = [&](size_t bytes) -> void* {
    void* p = ws + off;
    off += (bytes + 63) & ~(size_t)63;
    return p;
  };
  const size_t BIGPK = (size_t)32 * 256 * 64 * 8 * 2;  // 8.39 MB each
  u16* whh1p  = (u16*)alloc(BIGPK);
  u16* whh2p  = (u16*)alloc(BIGPK);
  u16* whh3p  = (u16*)alloc(BIGPK);
  u16* wih2p  = (u16*)alloc(BIGPK);
  u16* wih3p  = (u16*)alloc(BIGPK);
  u16* wfusep = (u16*)alloc(BIGPK);
  u16* wih1p  = (u16*)alloc((size_t)6 * 256 * 64 * 8 * 2);
  u16* wdecp  = (u16*)alloc((size_t)32 * 11 * 64 * 8 * 2);
  u16* seedp  = (u16*)alloc((size_t)NSEED * NB * NINP * 2);
  u16* h1b    = (u16*)alloc((size_t)2 * NB * NH * 2);
  u16* h2b    = (u16*)alloc((size_t)2 * NB * NH * 2);
  u16* h3h    = (u16*)alloc((size_t)NTT * NB * NH * 2);   // 33.5 MB
  float* b1s  = (float*)alloc((size_t)NG * 4);
  float* b1g  = (float*)alloc((size_t)NG * 4);
  float* b2   = (float*)alloc((size_t)NG * 4);
  float* b3   = (float*)alloc((size_t)NG * 4);
  float* bdecp = (float*)alloc((size_t)NOUTP * 4);
  int* cnt    = (int*)alloc((size_t)256 * 4);   // epoch counter (line-isolated)
  // Wfuse fp32 temp aliases h3h (prep finishes before lstm_main writes h3h,
  // and lstm_main fully rewrites h3h before dec_kernel reads it).
  float* wftmp = (float*)h3h;

  // ---- prep ----
  pack_mat<<<dim3(2048), dim3(256), 0, stream>>>(Whh1, whh1p, 32);
  pack_mat<<<dim3(2048), dim3(256), 0, stream>>>(Whh2, whh2p, 32);
  pack_mat<<<dim3(2048), dim3(256), 0, stream>>>(Whh3, whh3p, 32);
  pack_mat<<<dim3(2048), dim3(256), 0, stream>>>(Wih2, wih2p, 32);
  pack_mat<<<dim3(2048), dim3(256), 0, stream>>>(Wih3, wih3p, 32);
  pack_wih1<<<dim3(384), dim3(256), 0, stream>>>(Wih1, wih1p);
  wfuse_kernel<<<dim3(4096, 4), dim3(256), 0, stream>>>(Wih1, Wdec, wftmp);
  pack_mat<<<dim3(2048), dim3(256), 0, stream>>>(wftmp, wfusep, 32);
  pack_wdec<<<dim3(88), dim3(256), 0, stream>>>(Wdec, wdecp);
  pack_seed<<<dim3(3072), dim3(256), 0, stream>>>(seed, seedp);
  prep_bias<<<dim3(16), dim3(256), 0, stream>>>(bih1, bhh1, bih2, bhh2, bih3, bhh3,
                                                Wih1, bdec, b1s, b1g, b2, b3, bdecp, cnt);
  // ---- recurrence ----
  lstm_main<<<dim3(NWG), dim3(256), 0, stream>>>(
      whh1p, whh2p, whh3p, wih2p, wih3p, wfusep, wih1p, seedp,
      h1b, h2b, h3h, b1s, b1g, b2, b3, cnt);
  // ---- batched decoder ----
  dec_kernel<<<dim3(1408), dim3(256), 0, stream>>>(h3h, wdecp, bdecp, (float*)d_out);
}

// Round 6
// 11328.577 us; speedup vs baseline: 1.0029x; 1.0029x over previous
//
#include <hip/hip_runtime.h>
#include <hip/hip_bf16.h>
#include <math.h>

// Problem constants
#define NB    32    // batch
#define NSEED 128
#define NTT   512   // total timesteps (128 seed + 384 gen)
#define NIN   171
#define NINP  192   // padded input dim (6 k-tiles of 32)
#define NH    1024
#define NG    4096  // 4*H
#define NOUT  171
#define NOUTP 176   // padded to 11 n-tiles of 16
#define NWG   256
#define HS    (NB * NH)   // one h snapshot: 32768 elems (64 KB bf16)

typedef unsigned short u16;
typedef unsigned int u32;
typedef __attribute__((ext_vector_type(8))) short bf16x8;
typedef __attribute__((ext_vector_type(4))) float f32x4;

__device__ __host__ inline u16 f2bf(float x) {
  union { float f; unsigned u; } v; v.f = x;
  unsigned r = v.u + 0x7FFFu + ((v.u >> 16) & 1u);
  return (u16)(r >> 16);
}

// ---------------------------------------------------------------------------
// Packing kernels (unchanged)
// ---------------------------------------------------------------------------
__global__ void pack_mat(const float* __restrict__ src, u16* __restrict__ dst, int ktiles) {
  int id = blockIdx.x * 256 + threadIdx.x;
  int total = ktiles * 256 * 64;
  if (id >= total) return;
  int lane = id & 63;
  int nt = (id >> 6) & 255;
  int kt = id >> 14;
  int c = lane & 15, q = lane >> 4;
  int r = (c & 3) * 1024 + nt * 4 + (c >> 2);
  int K = ktiles * 32;
  const float* s = src + (size_t)r * K + kt * 32 + q * 8;
  __attribute__((aligned(16))) u16 o[8];
#pragma unroll
  for (int j = 0; j < 8; ++j) o[j] = f2bf(s[j]);
  *(bf16x8*)(dst + (size_t)id * 8) = *(const bf16x8*)o;
}

__global__ void pack_wih1(const float* __restrict__ src, u16* __restrict__ dst) {
  int id = blockIdx.x * 256 + threadIdx.x;
  if (id >= 6 * 256 * 64) return;
  int lane = id & 63;
  int nt = (id >> 6) & 255;
  int kt = id >> 14;
  int c = lane & 15, q = lane >> 4;
  int r = (c & 3) * 1024 + nt * 4 + (c >> 2);
  int k0 = kt * 32 + q * 8;
  __attribute__((aligned(16))) u16 o[8];
#pragma unroll
  for (int j = 0; j < 8; ++j) {
    int k = k0 + j;
    o[j] = (k < NIN) ? f2bf(src[(size_t)r * NIN + k]) : (u16)0;
  }
  *(bf16x8*)(dst + (size_t)id * 8) = *(const bf16x8*)o;
}

__global__ void pack_wdec(const float* __restrict__ src, u16* __restrict__ dst) {
  int id = blockIdx.x * 256 + threadIdx.x;
  if (id >= 32 * 11 * 64) return;
  int lane = id & 63;
  int nt = (id >> 6) % 11;
  int kt = (id >> 6) / 11;
  int c = lane & 15, q = lane >> 4;
  int r = nt * 16 + c;  // output column
  int k0 = kt * 32 + q * 8;
  __attribute__((aligned(16))) u16 o[8];
#pragma unroll
  for (int j = 0; j < 8; ++j) {
    o[j] = (r < NOUT) ? f2bf(src[(size_t)r * NH + k0 + j]) : (u16)0;
  }
  *(bf16x8*)(dst + (size_t)id * 8) = *(const bf16x8*)o;
}

__global__ void pack_seed(const float* __restrict__ src, u16* __restrict__ dst) {
  int id = blockIdx.x * 256 + threadIdx.x;
  if (id >= NSEED * NB * NINP) return;
  int kp = id % NINP;
  int b = (id / NINP) % NB;
  int t = id / (NINP * NB);
  float v = (kp < NIN) ? src[((size_t)b * NSEED + t) * NIN + kp] : 0.f;
  dst[id] = f2bf(v);
}

__global__ void wfuse_kernel(const float* __restrict__ wih1, const float* __restrict__ wdec,
                             float* __restrict__ tmp) {
  int n = blockIdx.x;
  int k = blockIdx.y * 256 + threadIdx.x;
  const float* wr = wih1 + (size_t)n * NIN;
  float s = 0.f;
  for (int i = 0; i < NIN; ++i) s += wr[i] * wdec[(size_t)i * NH + k];
  tmp[(size_t)n * NH + k] = s;
}

__global__ void prep_bias(const float* bih1, const float* bhh1, const float* bih2, const float* bhh2,
                          const float* bih3, const float* bhh3, const float* __restrict__ wih1,
                          const float* __restrict__ bdec_in,
                          float* b1s, float* b1g, float* b2, float* b3, float* bdecp) {
  int n = blockIdx.x * 256 + threadIdx.x;
  if (n >= NG) return;
  int wgi = n >> 4, c = n & 15;
  int r = (c & 3) * 1024 + wgi * 4 + (c >> 2);
  float v1 = bih1[r] + bhh1[r];
  b1s[n] = v1;
  float bf = 0.f;
  for (int i = 0; i < NIN; ++i) bf += wih1[(size_t)r * NIN + i] * bdec_in[i];
  b1g[n] = v1 + bf;
  b2[n] = bih2[r] + bhh2[r];
  b3[n] = bih3[r] + bhh3[r];
  if (n < NOUTP) bdecp[n] = (n < NOUT) ? bdec_in[n] : 0.f;
}

#define MFMA_BF16 __builtin_amdgcn_mfma_f32_16x16x32_bf16

// K=1024 matmul, B from global packed stream (L2-resident weights), x cached.
__device__ __forceinline__ void mm32g(f32x4& d0, f32x4& d1, const u16* __restrict__ wb,
                                      const u16* __restrict__ x, int wv, int lane) {
  int m = lane & 15, q = lane >> 4;
  const u16* xa = x + m * NH + q * 8;
  const u16* xb = xa + 16 * NH;
  const u16* wp = wb + lane * 8 + (size_t)wv * 131072;
#pragma unroll
  for (int i = 0; i < 8; ++i) {
    bf16x8 w = *(const bf16x8*)(wp + (size_t)i * 524288);
    bf16x8 a0 = *(const bf16x8*)(xa + (wv + 4 * i) * 32);
    bf16x8 a1 = *(const bf16x8*)(xb + (wv + 4 * i) * 32);
    d0 = MFMA_BF16(a0, w, d0, 0, 0, 0);
    d1 = MFMA_BF16(a1, w, d1, 0, 0, 0);
  }
}

// K=1024 matmul, B from LDS slice, x cached.
__device__ __forceinline__ void mm32l(f32x4& d0, f32x4& d1, const u16* wl,
                                      const u16* __restrict__ x, int wv, int lane) {
  int m = lane & 15, q = lane >> 4;
  const u16* xa = x + m * NH + q * 8;
  const u16* xb = xa + 16 * NH;
  const u16* wp = wl + lane * 8 + wv * 512;
#pragma unroll
  for (int i = 0; i < 8; ++i) {
    bf16x8 w = *(const bf16x8*)(wp + i * 2048);
    bf16x8 a0 = *(const bf16x8*)(xa + (wv + 4 * i) * 32);
    bf16x8 a1 = *(const bf16x8*)(xb + (wv + 4 * i) * 32);
    d0 = MFMA_BF16(a0, w, d0, 0, 0, 0);
    d1 = MFMA_BF16(a1, w, d1, 0, 0, 0);
  }
}

// K=192 (6 ktiles) seed-phase Wih1 path.
__device__ __forceinline__ void mm6_glb(f32x4& d0, f32x4& d1, const u16* __restrict__ wbase,
                                        const u16* __restrict__ x, int wv, int lane) {
  int m = lane & 15, q = lane >> 4;
  const u16* xa = x + m * NINP + q * 8;
  const u16* xb = xa + 16 * NINP;
  const u16* wb = wbase + lane * 8;
#pragma unroll
  for (int i = 0; i < 2; ++i) {
    int kt = wv + 4 * i;
    if (kt >= 6) break;
    bf16x8 w = *(const bf16x8*)(wb + (size_t)kt * 131072);
    bf16x8 a0 = *(const bf16x8*)(xa + kt * 32);
    bf16x8 a1 = *(const bf16x8*)(xb + kt * 32);
    d0 = MFMA_BF16(a0, w, d0, 0, 0, 0);
    d1 = MFMA_BF16(a1, w, d1, 0, 0, 0);
  }
}

// ---------------------------------------------------------------------------
// Main persistent kernel. 256 WGs x 256 threads, 1 WG/CU.
// h state lives in WRITE-ONCE per-(layer,t) history buffers: every address is
// written exactly once per launch, so normal cached loads can never observe a
// stale value (kernel-start invalidate + no address reuse). Producers publish
// with sc1 write-through stores; the per-stage flag store is a true RELEASE
// (wbl2-backed), so flag visibility implies data visibility at L3. Readers
// poll relaxed and use plain cached loads: first reader per XCD fills from
// L3, the other 31 WGs hit local L2 -> the 32 MB/stage coherent fan-in of the
// sc1 design collapses to ~0.5 MB/stage.
// ---------------------------------------------------------------------------
__global__ __launch_bounds__(256, 1) void lstm_main(
    const u16* __restrict__ whh1, const u16* __restrict__ whh2, const u16* __restrict__ whh3,
    const u16* __restrict__ wih2, const u16* __restrict__ wih3,
    const u16* __restrict__ wfuse, const u16* __restrict__ wih1,
    const u16* __restrict__ seedp,
    u16* __restrict__ h1h, u16* __restrict__ h2h, u16* __restrict__ h3h,
    const float* __restrict__ b1s, const float* __restrict__ b1g,
    const float* __restrict__ b2, const float* __restrict__ b3,
    int* __restrict__ flags)
{
  __shared__ u16  wlds[3 * 16384];     // 96 KB: wih2 | wih3 | wfuse slices
  __shared__ float red[4][64][9];      // split-K reduction, stride 9 = no 16-way conflicts
  __shared__ float gbuf[32][16];       // gates (b, packed col)
  __shared__ float cst[3][32][4];      // cell state: layer, batch, local j

  int wg = blockIdx.x;
  int tid = threadIdx.x;
  int wv = tid >> 6, lane = tid & 63;

  // ---- stage phase-B weight slices into LDS (one time) ----
  {
    const u16* srcs[3] = { wih2 + (size_t)wg * 512, wih3 + (size_t)wg * 512,
                           wfuse + (size_t)wg * 512 };
#pragma unroll
    for (int m = 0; m < 3; ++m) {
      for (int i = tid; i < 2048; i += 256) {          // 32 kt * 64 lanes
        int kt = i >> 6, ln = i & 63;
        *(bf16x8*)&wlds[m * 16384 + (kt * 64 + ln) * 8] =
            *(const bf16x8*)(srcs[m] + ((size_t)kt * 16384 + ln) * 8);
      }
    }
    float* cp = &cst[0][0][0];
    for (int i = tid; i < 3 * 32 * 4; i += 256) cp[i] = 0.f;
  }
  __syncthreads();

  // per-thread bias preload (epilogue uses c = tid & 15)
  int c0 = tid & 15;
  float bv_s  = b1s[wg * 16 + c0];
  float bv_g  = b1g[wg * 16 + c0];
  float bv_2  = b2 [wg * 16 + c0];
  float bv_3  = b3 [wg * 16 + c0];

  const u16* whhg[3] = { whh1 + (size_t)wg * 512, whh2 + (size_t)wg * 512,
                         whh3 + (size_t)wg * 512 };
  const u16* wih1g = wih1 + (size_t)wg * 512;

  int ep = 0;  // completed stages
  for (int t = 0; t < NTT; ++t) {
    for (int l = 0; l < 3; ++l) {
      f32x4 d0 = {0.f, 0.f, 0.f, 0.f}, d1 = {0.f, 0.f, 0.f, 0.f};
      bool isseed = (t < NSEED);

      // ---- pre-barrier work (inputs >= 3 stages old, cached loads) ----
      if (l == 0 && isseed)
        mm6_glb(d0, d1, wih1g, seedp + (size_t)t * NB * NINP, wv, lane);
      if (t > 0) {            // recurrent term h_l[t-1] @ Whh_l^T
        const u16* hs = (l == 0) ? h1h + (size_t)(t - 1) * HS
                     : (l == 1) ? h2h + (size_t)(t - 1) * HS
                                : h3h + (size_t)(t - 1) * HS;
        mm32g(d0, d1, whhg[l], hs, wv, lane);
      }

      // ---- barrier wait (relaxed poll; producer flag is a RELEASE) ----
      bool skipwait = (l == 0 && isseed);
      if (ep > 0 && !skipwait) {
        if (tid < 64) {
          const int* fp = flags + (tid << 6);   // 4 flags/lane, 64 B apart
          for (;;) {
            int f0 = __hip_atomic_load(fp +  0, __ATOMIC_RELAXED, __HIP_MEMORY_SCOPE_AGENT);
            int f1 = __hip_atomic_load(fp + 16, __ATOMIC_RELAXED, __HIP_MEMORY_SCOPE_AGENT);
            int f2 = __hip_atomic_load(fp + 32, __ATOMIC_RELAXED, __HIP_MEMORY_SCOPE_AGENT);
            int f3 = __hip_atomic_load(fp + 48, __ATOMIC_RELAXED, __HIP_MEMORY_SCOPE_AGENT);
            int mn = min(min(f0, f1), min(f2, f3));
            if (__all(mn >= ep)) break;
            __builtin_amdgcn_s_sleep(1);
          }
        }
        __syncthreads();
        asm volatile("" ::: "memory");  // no load hoisting above the wait
      }

      // ---- post-barrier: fresh input term (B from LDS, x cached) ----
      if (l == 0) {
        if (!isseed)
          mm32l(d0, d1, &wlds[2 * 16384], h3h + (size_t)(t - 1) * HS, wv, lane);
      } else {
        const u16* xs = (l == 1) ? h1h + (size_t)t * HS
                                 : h2h + (size_t)t * HS;
        mm32l(d0, d1, &wlds[(l - 1) * 16384], xs, wv, lane);
      }

      // ---- reduce the 4 waves' split-K partials via LDS ----
#pragma unroll
      for (int r = 0; r < 4; ++r) { red[wv][lane][r] = d0[r]; red[wv][lane][4 + r] = d1[r]; }
      __syncthreads();
      {
        int c = tid & 15, brow = tid >> 4;   // brow 0..15
        float bv = (l == 0) ? (isseed ? bv_s : bv_g) : (l == 1) ? bv_2 : bv_3;
        int srcl = ((brow >> 2) << 4) | c;   // D-frag: col=lane&15, row=(lane>>4)*4+reg
#pragma unroll
        for (int mt = 0; mt < 2; ++mt) {
          int b = brow + mt * 16;
          int idx = mt * 4 + (brow & 3);
          gbuf[b][c] = red[0][srcl][idx] + red[1][srcl][idx] +
                       red[2][srcl][idx] + red[3][srcl][idx] + bv;
        }
      }
      __syncthreads();

      // ---- pointwise LSTM cell; h published via relaxed sc1 u32 stores ----
      if (tid < 128) {
        int b = tid & 31, jl = tid >> 5;
        float gi = gbuf[b][jl * 4 + 0], gf = gbuf[b][jl * 4 + 1];
        float gg = gbuf[b][jl * 4 + 2], go = gbuf[b][jl * 4 + 3];
        float si = 1.f / (1.f + expf(-gi));
        float sf = 1.f / (1.f + expf(-gf));
        float so = 1.f / (1.f + expf(-go));
        float cn = sf * cst[l][b][jl] + si * tanhf(gg);
        cst[l][b][jl] = cn;
        float hn = so * tanhf(cn);
        unsigned hv = (unsigned)f2bf(hn);
        // pair (jl even, jl odd) lives at lane ^ 32 within the same wave
        unsigned other = (unsigned)__shfl_xor((int)hv, 32, 64);
        if (lane < 32) {
          unsigned val = hv | (other << 16);
          int w01 = tid >> 6;  // 0 -> cols (0,1), 1 -> cols (2,3)
          u16* hdst = (l == 0) ? h1h + (size_t)t * HS
                    : (l == 1) ? h2h + (size_t)t * HS
                               : h3h + (size_t)t * HS;
          u32* hp = (u32*)hdst + (size_t)b * 512 + wg * 2 + w01;
          __hip_atomic_store(hp, val, __ATOMIC_RELAXED, __HIP_MEMORY_SCOPE_AGENT);
        }
      }

      // ---- signal stage completion: TRUE RELEASE (publishes h stores) ----
      __syncthreads();   // all waves' stores vmcnt-drained
      ++ep;
      if (tid == 0)
        __hip_atomic_store(&flags[wg << 4], ep, __ATOMIC_RELEASE, __HIP_MEMORY_SCOPE_AGENT);
    }
  }
}

// ---------------------------------------------------------------------------
// Batched decoder: out[b][t][o] = h3[t] @ Wdec^T + bdec for all 512 steps.
// ---------------------------------------------------------------------------
__global__ __launch_bounds__(256) void dec_kernel(
    const u16* __restrict__ h3h, const u16* __restrict__ wdec,
    const float* __restrict__ bdecp, float* __restrict__ out)
{
  int task = blockIdx.x * 4 + (threadIdx.x >> 6);
  int lane = threadIdx.x & 63;
  int nt = task % 11, rt = task / 11;
  if (rt >= NTT) return;
  int m = lane & 15, q = lane >> 4;
  const u16* xa = h3h + ((size_t)rt * 32 + m) * NH + q * 8;
  const u16* xb = xa + (size_t)16 * NH;
  f32x4 d0 = {0.f, 0.f, 0.f, 0.f}, d1 = {0.f, 0.f, 0.f, 0.f};
  for (int kt = 0; kt < 32; ++kt) {
    bf16x8 bf = *(const bf16x8*)(wdec + ((size_t)(kt * 11 + nt) * 64 + lane) * 8);
    bf16x8 a0 = *(const bf16x8*)(xa + kt * 32);
    bf16x8 a1 = *(const bf16x8*)(xb + kt * 32);
    d0 = MFMA_BF16(a0, bf, d0, 0, 0, 0);
    d1 = MFMA_BF16(a1, bf, d1, 0, 0, 0);
  }
  int o = nt * 16 + m;
  if (o >= NOUT) return;
  float bv = bdecp[o];
#pragma unroll
  for (int reg = 0; reg < 4; ++reg) {
    int row0 = rt * 32 + q * 4 + reg;          // row = t*32 + b
    out[(((size_t)(row0 & 31)) * NTT + (row0 >> 5)) * NOUT + o] = d0[reg] + bv;
    int row1 = row0 + 16;
    out[(((size_t)(row1 & 31)) * NTT + (row1 >> 5)) * NOUT + o] = d1[reg] + bv;
  }
}

// ---------------------------------------------------------------------------
extern "C" void kernel_launch(void* const* d_in, const int* in_sizes, int n_in,
                              void* d_out, int out_size, void* d_ws, size_t ws_size,
                              hipStream_t stream) {
  const float* seed = (const float*)d_in[0];
  const float* Wih1 = (const float*)d_in[1];
  const float* Whh1 = (const float*)d_in[2];
  const float* bih1 = (const float*)d_in[3];
  const float* bhh1 = (const float*)d_in[4];
  const float* Wih2 = (const float*)d_in[5];
  const float* Whh2 = (const float*)d_in[6];
  const float* bih2 = (const float*)d_in[7];
  const float* bhh2 = (const float*)d_in[8];
  const float* Wih3 = (const float*)d_in[9];
  const float* Whh3 = (const float*)d_in[10];
  const float* bih3 = (const float*)d_in[11];
  const float* bhh3 = (const float*)d_in[12];
  const float* Wdec = (const float*)d_in[13];
  const float* bdec = (const float*)d_in[14];

  char* ws = (char*)d_ws;
  size_t off = 0;
  auto alloc = [&](size_t bytes) -> void* {
    void* p = ws + off;
    off += (bytes + 63) & ~(size_t)63;
    return p;
  };
  const size_t BIGPK = (size_t)32 * 256 * 64 * 8 * 2;  // 8.39 MB each
  u16* whh1p  = (u16*)alloc(BIGPK);
  u16* whh2p  = (u16*)alloc(BIGPK);
  u16* whh3p  = (u16*)alloc(BIGPK);
  u16* wih2p  = (u16*)alloc(BIGPK);
  u16* wih3p  = (u16*)alloc(BIGPK);
  u16* wfusep = (u16*)alloc(BIGPK);
  u16* wih1p  = (u16*)alloc((size_t)6 * 256 * 64 * 8 * 2);
  u16* wdecp  = (u16*)alloc((size_t)32 * 11 * 64 * 8 * 2);
  u16* seedp  = (u16*)alloc((size_t)NSEED * NB * NINP * 2);
  u16* h1h    = (u16*)alloc((size_t)NTT * HS * 2);   // 33.5 MB, write-once
  u16* h2h    = (u16*)alloc((size_t)NTT * HS * 2);   // 33.5 MB, write-once
  u16* h3h    = (u16*)alloc((size_t)NTT * HS * 2);   // 33.5 MB, write-once
  float* wftmp = (float*)alloc((size_t)NG * NH * 4); // 16.8 MB (no aliasing!)
  float* b1s  = (float*)alloc((size_t)NG * 4);
  float* b1g  = (float*)alloc((size_t)NG * 4);
  float* b2   = (float*)alloc((size_t)NG * 4);
  float* b3   = (float*)alloc((size_t)NG * 4);
  float* bdecp = (float*)alloc((size_t)NOUTP * 4);
  int* flags  = (int*)alloc((size_t)NWG * 16 * 4);   // one flag per 64 B line

  // ---- prep ----
  pack_mat<<<dim3(2048), dim3(256), 0, stream>>>(Whh1, whh1p, 32);
  pack_mat<<<dim3(2048), dim3(256), 0, stream>>>(Whh2, whh2p, 32);
  pack_mat<<<dim3(2048), dim3(256), 0, stream>>>(Whh3, whh3p, 32);
  pack_mat<<<dim3(2048), dim3(256), 0, stream>>>(Wih2, wih2p, 32);
  pack_mat<<<dim3(2048), dim3(256), 0, stream>>>(Wih3, wih3p, 32);
  pack_wih1<<<dim3(384), dim3(256), 0, stream>>>(Wih1, wih1p);
  wfuse_kernel<<<dim3(4096, 4), dim3(256), 0, stream>>>(Wih1, Wdec, wftmp);
  pack_mat<<<dim3(2048), dim3(256), 0, stream>>>(wftmp, wfusep, 32);
  pack_wdec<<<dim3(88), dim3(256), 0, stream>>>(Wdec, wdecp);
  pack_seed<<<dim3(3072), dim3(256), 0, stream>>>(seed, seedp);
  prep_bias<<<dim3(16), dim3(256), 0, stream>>>(bih1, bhh1, bih2, bhh2, bih3, bhh3,
                                                Wih1, bdec, b1s, b1g, b2, b3, bdecp);
  // ---- recurrence ----
  lstm_main<<<dim3(NWG), dim3(256), 0, stream>>>(
      whh1p, whh2p, whh3p, wih2p, wih3p, wfusep, wih1p, seedp,
      h1h, h2h, h3h, b1s, b1g, b2, b3, flags);
  // ---- batched decoder ----
  dec_kernel<<<dim3(1408), dim3(256), 0, stream>>>(h3h, wdecp, bdecp, (float*)d_out);
}

// Round 8
// 8933.760 us; speedup vs baseline: 1.2718x; 1.2681x over previous
//
#include <hip/hip_runtime.h>
#include <hip/hip_bf16.h>
#include <math.h>

// Problem constants
#define NB    32    // batch
#define NSEED 128
#define NTT   512   // total timesteps (128 seed + 384 gen)
#define NIN   171
#define NINP  192   // padded input dim (6 k-tiles of 32)
#define NH    1024
#define NG    4096  // 4*H
#define NOUT  171
#define NOUTP 176   // padded to 11 n-tiles of 16
#define NWG   256
#define HS    (NB * NH)   // one h snapshot: 32768 elems (64 KB bf16)

typedef unsigned short u16;
typedef unsigned int u32;
typedef __attribute__((ext_vector_type(8))) short bf16x8;
typedef __attribute__((ext_vector_type(4))) float f32x4;

__device__ __host__ inline u16 f2bf(float x) {
  union { float f; unsigned u; } v; v.f = x;
  unsigned r = v.u + 0x7FFFu + ((v.u >> 16) & 1u);
  return (u16)(r >> 16);
}

// ---------------------------------------------------------------------------
// Packing kernels (unchanged)
// ---------------------------------------------------------------------------
__global__ void pack_mat(const float* __restrict__ src, u16* __restrict__ dst, int ktiles) {
  int id = blockIdx.x * 256 + threadIdx.x;
  int total = ktiles * 256 * 64;
  if (id >= total) return;
  int lane = id & 63;
  int nt = (id >> 6) & 255;
  int kt = id >> 14;
  int c = lane & 15, q = lane >> 4;
  int r = (c & 3) * 1024 + nt * 4 + (c >> 2);
  int K = ktiles * 32;
  const float* s = src + (size_t)r * K + kt * 32 + q * 8;
  __attribute__((aligned(16))) u16 o[8];
#pragma unroll
  for (int j = 0; j < 8; ++j) o[j] = f2bf(s[j]);
  *(bf16x8*)(dst + (size_t)id * 8) = *(const bf16x8*)o;
}

__global__ void pack_wih1(const float* __restrict__ src, u16* __restrict__ dst) {
  int id = blockIdx.x * 256 + threadIdx.x;
  if (id >= 6 * 256 * 64) return;
  int lane = id & 63;
  int nt = (id >> 6) & 255;
  int kt = id >> 14;
  int c = lane & 15, q = lane >> 4;
  int r = (c & 3) * 1024 + nt * 4 + (c >> 2);
  int k0 = kt * 32 + q * 8;
  __attribute__((aligned(16))) u16 o[8];
#pragma unroll
  for (int j = 0; j < 8; ++j) {
    int k = k0 + j;
    o[j] = (k < NIN) ? f2bf(src[(size_t)r * NIN + k]) : (u16)0;
  }
  *(bf16x8*)(dst + (size_t)id * 8) = *(const bf16x8*)o;
}

__global__ void pack_wdec(const float* __restrict__ src, u16* __restrict__ dst) {
  int id = blockIdx.x * 256 + threadIdx.x;
  if (id >= 32 * 11 * 64) return;
  int lane = id & 63;
  int nt = (id >> 6) % 11;
  int kt = (id >> 6) / 11;
  int c = lane & 15, q = lane >> 4;
  int r = nt * 16 + c;  // output column
  int k0 = kt * 32 + q * 8;
  __attribute__((aligned(16))) u16 o[8];
#pragma unroll
  for (int j = 0; j < 8; ++j) {
    o[j] = (r < NOUT) ? f2bf(src[(size_t)r * NH + k0 + j]) : (u16)0;
  }
  *(bf16x8*)(dst + (size_t)id * 8) = *(const bf16x8*)o;
}

__global__ void pack_seed(const float* __restrict__ src, u16* __restrict__ dst) {
  int id = blockIdx.x * 256 + threadIdx.x;
  if (id >= NSEED * NB * NINP) return;
  int kp = id % NINP;
  int b = (id / NINP) % NB;
  int t = id / (NINP * NB);
  float v = (kp < NIN) ? src[((size_t)b * NSEED + t) * NIN + kp] : 0.f;
  dst[id] = f2bf(v);
}

__global__ void wfuse_kernel(const float* __restrict__ wih1, const float* __restrict__ wdec,
                             float* __restrict__ tmp) {
  int n = blockIdx.x;
  int k = blockIdx.y * 256 + threadIdx.x;
  const float* wr = wih1 + (size_t)n * NIN;
  float s = 0.f;
  for (int i = 0; i < NIN; ++i) s += wr[i] * wdec[(size_t)i * NH + k];
  tmp[(size_t)n * NH + k] = s;
}

__global__ void prep_bias(const float* bih1, const float* bhh1, const float* bih2, const float* bhh2,
                          const float* bih3, const float* bhh3, const float* __restrict__ wih1,
                          const float* __restrict__ bdec_in,
                          float* b1s, float* b1g, float* b2, float* b3, float* bdecp) {
  int n = blockIdx.x * 256 + threadIdx.x;
  if (n >= NG) return;
  int wgi = n >> 4, c = n & 15;
  int r = (c & 3) * 1024 + wgi * 4 + (c >> 2);
  float v1 = bih1[r] + bhh1[r];
  b1s[n] = v1;
  float bf = 0.f;
  for (int i = 0; i < NIN; ++i) bf += wih1[(size_t)r * NIN + i] * bdec_in[i];
  b1g[n] = v1 + bf;
  b2[n] = bih2[r] + bhh2[r];
  b3[n] = bih3[r] + bhh3[r];
  if (n < NOUTP) bdecp[n] = (n < NOUT) ? bdec_in[n] : 0.f;
}

#define MFMA_BF16 __builtin_amdgcn_mfma_f32_16x16x32_bf16

// K=1024 matmul, B from global packed stream (L2-resident weights), x cached.
__device__ __forceinline__ void mm32g(f32x4& d0, f32x4& d1, const u16* __restrict__ wb,
                                      const u16* __restrict__ x, int wv, int lane) {
  int m = lane & 15, q = lane >> 4;
  const u16* xa = x + m * NH + q * 8;
  const u16* xb = xa + 16 * NH;
  const u16* wp = wb + lane * 8 + (size_t)wv * 131072;
#pragma unroll
  for (int i = 0; i < 8; ++i) {
    bf16x8 w = *(const bf16x8*)(wp + (size_t)i * 524288);
    bf16x8 a0 = *(const bf16x8*)(xa + (wv + 4 * i) * 32);
    bf16x8 a1 = *(const bf16x8*)(xb + (wv + 4 * i) * 32);
    d0 = MFMA_BF16(a0, w, d0, 0, 0, 0);
    d1 = MFMA_BF16(a1, w, d1, 0, 0, 0);
  }
}

// K=1024 matmul, B from LDS slice, x cached.
__device__ __forceinline__ void mm32l(f32x4& d0, f32x4& d1, const u16* wl,
                                      const u16* __restrict__ x, int wv, int lane) {
  int m = lane & 15, q = lane >> 4;
  const u16* xa = x + m * NH + q * 8;
  const u16* xb = xa + 16 * NH;
  const u16* wp = wl + lane * 8 + wv * 512;
#pragma unroll
  for (int i = 0; i < 8; ++i) {
    bf16x8 w = *(const bf16x8*)(wp + i * 2048);
    bf16x8 a0 = *(const bf16x8*)(xa + (wv + 4 * i) * 32);
    bf16x8 a1 = *(const bf16x8*)(xb + (wv + 4 * i) * 32);
    d0 = MFMA_BF16(a0, w, d0, 0, 0, 0);
    d1 = MFMA_BF16(a1, w, d1, 0, 0, 0);
  }
}

// K=192 (6 ktiles) seed-phase Wih1 path.
__device__ __forceinline__ void mm6_glb(f32x4& d0, f32x4& d1, const u16* __restrict__ wbase,
                                        const u16* __restrict__ x, int wv, int lane) {
  int m = lane & 15, q = lane >> 4;
  const u16* xa = x + m * NINP + q * 8;
  const u16* xb = xa + 16 * NINP;
  const u16* wb = wbase + lane * 8;
#pragma unroll
  for (int i = 0; i < 2; ++i) {
    int kt = wv + 4 * i;
    if (kt >= 6) break;
    bf16x8 w = *(const bf16x8*)(wb + (size_t)kt * 131072);
    bf16x8 a0 = *(const bf16x8*)(xa + kt * 32);
    bf16x8 a1 = *(const bf16x8*)(xb + kt * 32);
    d0 = MFMA_BF16(a0, w, d0, 0, 0, 0);
    d1 = MFMA_BF16(a1, w, d1, 0, 0, 0);
  }
}

// ---------------------------------------------------------------------------
// Main persistent kernel. 256 WGs x 256 threads, 1 WG/CU.
// h state: WRITE-ONCE per-(layer,t) history buffers -> plain cached loads can
// never observe stale data (kernel-start invalidate + no address reuse).
// Publish protocol (fence-free release):
//   1. h values stored with RETURNING __hip_atomic_exchange (relaxed, agent).
//      The live return value forces the sc0 form, whose vmcnt retires only
//      when the RMW has executed at the coherent point (L3). Compiler-visible
//      => the __syncthreads() barrier drain (vmcnt(0)) provably covers it.
//   2. __syncthreads()  -> every wave's exchanges confirmed at L3.
//   3. tid0 stores the flag RELAXED. Data-before-flag is hardware-ordered
//      with ZERO cache-maintenance ops (no buffer_wbl2 / buffer_inv).
// ---------------------------------------------------------------------------
__global__ __launch_bounds__(256, 1) void lstm_main(
    const u16* __restrict__ whh1, const u16* __restrict__ whh2, const u16* __restrict__ whh3,
    const u16* __restrict__ wih2, const u16* __restrict__ wih3,
    const u16* __restrict__ wfuse, const u16* __restrict__ wih1,
    const u16* __restrict__ seedp,
    u16* __restrict__ h1h, u16* __restrict__ h2h, u16* __restrict__ h3h,
    const float* __restrict__ b1s, const float* __restrict__ b1g,
    const float* __restrict__ b2, const float* __restrict__ b3,
    int* __restrict__ flags)
{
  __shared__ u16  wlds[3 * 16384];     // 96 KB: wih2 | wih3 | wfuse slices
  __shared__ float red[4][64][9];      // split-K reduction, stride 9 = conflict-free
  __shared__ float gbuf[32][16];       // gates (b, packed col)
  __shared__ float cst[3][32][4];      // cell state: layer, batch, local j

  int wg = blockIdx.x;
  int tid = threadIdx.x;
  int wv = tid >> 6, lane = tid & 63;

  // ---- stage phase-B weight slices into LDS (one time) ----
  {
    const u16* srcs[3] = { wih2 + (size_t)wg * 512, wih3 + (size_t)wg * 512,
                           wfuse + (size_t)wg * 512 };
#pragma unroll
    for (int m = 0; m < 3; ++m) {
      for (int i = tid; i < 2048; i += 256) {          // 32 kt * 64 lanes
        int kt = i >> 6, ln = i & 63;
        *(bf16x8*)&wlds[m * 16384 + (kt * 64 + ln) * 8] =
            *(const bf16x8*)(srcs[m] + ((size_t)kt * 16384 + ln) * 8);
      }
    }
    float* cp = &cst[0][0][0];
    for (int i = tid; i < 3 * 32 * 4; i += 256) cp[i] = 0.f;
  }
  __syncthreads();

  // per-thread bias preload (epilogue uses c = tid & 15)
  int c0 = tid & 15;
  float bv_s  = b1s[wg * 16 + c0];
  float bv_g  = b1g[wg * 16 + c0];
  float bv_2  = b2 [wg * 16 + c0];
  float bv_3  = b3 [wg * 16 + c0];

  const u16* whhg[3] = { whh1 + (size_t)wg * 512, whh2 + (size_t)wg * 512,
                         whh3 + (size_t)wg * 512 };
  const u16* wih1g = wih1 + (size_t)wg * 512;

  int ep = 0;  // completed stages
  for (int t = 0; t < NTT; ++t) {
    for (int l = 0; l < 3; ++l) {
      f32x4 d0 = {0.f, 0.f, 0.f, 0.f}, d1 = {0.f, 0.f, 0.f, 0.f};
      bool isseed = (t < NSEED);

      // ---- pre-barrier work (inputs >= 3 stages old, cached loads) ----
      if (l == 0 && isseed)
        mm6_glb(d0, d1, wih1g, seedp + (size_t)t * NB * NINP, wv, lane);
      if (t > 0) {            // recurrent term h_l[t-1] @ Whh_l^T
        const u16* hs = (l == 0) ? h1h + (size_t)(t - 1) * HS
                     : (l == 1) ? h2h + (size_t)(t - 1) * HS
                                : h3h + (size_t)(t - 1) * HS;
        mm32g(d0, d1, whhg[l], hs, wv, lane);
      }

      // ---- barrier wait (relaxed poll; publish is L3-confirmed) ----
      bool skipwait = (l == 0 && isseed);
      if (ep > 0 && !skipwait) {
        if (tid < 64) {
          const int* fp = flags + (tid << 6);   // 4 flags/lane, 64 B apart
          for (;;) {
            int f0 = __hip_atomic_load(fp +  0, __ATOMIC_RELAXED, __HIP_MEMORY_SCOPE_AGENT);
            int f1 = __hip_atomic_load(fp + 16, __ATOMIC_RELAXED, __HIP_MEMORY_SCOPE_AGENT);
            int f2 = __hip_atomic_load(fp + 32, __ATOMIC_RELAXED, __HIP_MEMORY_SCOPE_AGENT);
            int f3 = __hip_atomic_load(fp + 48, __ATOMIC_RELAXED, __HIP_MEMORY_SCOPE_AGENT);
            int mn = min(min(f0, f1), min(f2, f3));
            if (__all(mn >= ep)) break;
            __builtin_amdgcn_s_sleep(1);
          }
        }
        __syncthreads();
        asm volatile("" ::: "memory");  // no load hoisting above the wait
      }

      // ---- post-barrier: fresh input term (B from LDS, x cached) ----
      if (l == 0) {
        if (!isseed)
          mm32l(d0, d1, &wlds[2 * 16384], h3h + (size_t)(t - 1) * HS, wv, lane);
      } else {
        const u16* xs = (l == 1) ? h1h + (size_t)t * HS
                                 : h2h + (size_t)t * HS;
        mm32l(d0, d1, &wlds[(l - 1) * 16384], xs, wv, lane);
      }

      // ---- reduce the 4 waves' split-K partials via LDS ----
#pragma unroll
      for (int r = 0; r < 4; ++r) { red[wv][lane][r] = d0[r]; red[wv][lane][4 + r] = d1[r]; }
      __syncthreads();
      {
        int c = tid & 15, brow = tid >> 4;   // brow 0..15
        float bv = (l == 0) ? (isseed ? bv_s : bv_g) : (l == 1) ? bv_2 : bv_3;
        int srcl = ((brow >> 2) << 4) | c;   // D-frag: col=lane&15, row=(lane>>4)*4+reg
#pragma unroll
        for (int mt = 0; mt < 2; ++mt) {
          int b = brow + mt * 16;
          int idx = mt * 4 + (brow & 3);
          gbuf[b][c] = red[0][srcl][idx] + red[1][srcl][idx] +
                       red[2][srcl][idx] + red[3][srcl][idx] + bv;
        }
      }
      __syncthreads();

      // ---- pointwise LSTM cell; publish via RETURNING relaxed exchange ----
      if (tid < 128) {
        int b = tid & 31, jl = tid >> 5;
        float gi = gbuf[b][jl * 4 + 0], gf = gbuf[b][jl * 4 + 1];
        float gg = gbuf[b][jl * 4 + 2], go = gbuf[b][jl * 4 + 3];
        float si = 1.f / (1.f + expf(-gi));
        float sf = 1.f / (1.f + expf(-gf));
        float so = 1.f / (1.f + expf(-go));
        float cn = sf * cst[l][b][jl] + si * tanhf(gg);
        cst[l][b][jl] = cn;
        float hn = so * tanhf(cn);
        unsigned hv = (unsigned)f2bf(hn);
        // pair (jl even, jl odd) lives at lane ^ 32 within the same wave
        unsigned other = (unsigned)__shfl_xor((int)hv, 32, 64);
        if (lane < 32) {
          unsigned val = hv | (other << 16);
          int w01 = tid >> 6;  // 0 -> cols (0,1), 1 -> cols (2,3)
          u16* hdst = (l == 0) ? h1h + (size_t)t * HS
                    : (l == 1) ? h2h + (size_t)t * HS
                               : h3h + (size_t)t * HS;
          u32* hp = (u32*)hdst + (size_t)b * 512 + wg * 2 + w01;
          u32 old = __hip_atomic_exchange(hp, val, __ATOMIC_RELAXED,
                                          __HIP_MEMORY_SCOPE_AGENT);
          // keep the return alive: forces the sc0 (returning) encoding, so
          // vmcnt for this op retires only when the RMW executed at L3.
          asm volatile("" : : "v"(old));
        }
      }

      // ---- signal: syncthreads (vmcnt(0) drains the exchanges) + flag ----
      __syncthreads();
      ++ep;
      if (tid == 0)
        __hip_atomic_store(&flags[wg << 4], ep, __ATOMIC_RELAXED, __HIP_MEMORY_SCOPE_AGENT);
    }
  }
}

// ---------------------------------------------------------------------------
// Batched decoder: out[b][t][o] = h3[t] @ Wdec^T + bdec for all 512 steps.
// ---------------------------------------------------------------------------
__global__ __launch_bounds__(256) void dec_kernel(
    const u16* __restrict__ h3h, const u16* __restrict__ wdec,
    const float* __restrict__ bdecp, float* __restrict__ out)
{
  int task = blockIdx.x * 4 + (threadIdx.x >> 6);
  int lane = threadIdx.x & 63;
  int nt = task % 11, rt = task / 11;
  if (rt >= NTT) return;
  int m = lane & 15, q = lane >> 4;
  const u16* xa = h3h + ((size_t)rt * 32 + m) * NH + q * 8;
  const u16* xb = xa + (size_t)16 * NH;
  f32x4 d0 = {0.f, 0.f, 0.f, 0.f}, d1 = {0.f, 0.f, 0.f, 0.f};
  for (int kt = 0; kt < 32; ++kt) {
    bf16x8 bf = *(const bf16x8*)(wdec + ((size_t)(kt * 11 + nt) * 64 + lane) * 8);
    bf16x8 a0 = *(const bf16x8*)(xa + kt * 32);
    bf16x8 a1 = *(const bf16x8*)(xb + kt * 32);
    d0 = MFMA_BF16(a0, bf, d0, 0, 0, 0);
    d1 = MFMA_BF16(a1, bf, d1, 0, 0, 0);
  }
  int o = nt * 16 + m;
  if (o >= NOUT) return;
  float bv = bdecp[o];
#pragma unroll
  for (int reg = 0; reg < 4; ++reg) {
    int row0 = rt * 32 + q * 4 + reg;          // row = t*32 + b
    out[(((size_t)(row0 & 31)) * NTT + (row0 >> 5)) * NOUT + o] = d0[reg] + bv;
    int row1 = row0 + 16;
    out[(((size_t)(row1 & 31)) * NTT + (row1 >> 5)) * NOUT + o] = d1[reg] + bv;
  }
}

// ---------------------------------------------------------------------------
extern "C" void kernel_launch(void* const* d_in, const int* in_sizes, int n_in,
                              void* d_out, int out_size, void* d_ws, size_t ws_size,
                              hipStream_t stream) {
  const float* seed = (const float*)d_in[0];
  const float* Wih1 = (const float*)d_in[1];
  const float* Whh1 = (const float*)d_in[2];
  const float* bih1 = (const float*)d_in[3];
  const float* bhh1 = (const float*)d_in[4];
  const float* Wih2 = (const float*)d_in[5];
  const float* Whh2 = (const float*)d_in[6];
  const float* bih2 = (const float*)d_in[7];
  const float* bhh2 = (const float*)d_in[8];
  const float* Wih3 = (const float*)d_in[9];
  const float* Whh3 = (const float*)d_in[10];
  const float* bih3 = (const float*)d_in[11];
  const float* bhh3 = (const float*)d_in[12];
  const float* Wdec = (const float*)d_in[13];
  const float* bdec = (const float*)d_in[14];

  char* ws = (char*)d_ws;
  size_t off = 0;
  auto alloc = [&](size_t bytes) -> void* {
    void* p = ws + off;
    off += (bytes + 63) & ~(size_t)63;
    return p;
  };
  const size_t BIGPK = (size_t)32 * 256 * 64 * 8 * 2;  // 8.39 MB each
  u16* whh1p  = (u16*)alloc(BIGPK);
  u16* whh2p  = (u16*)alloc(BIGPK);
  u16* whh3p  = (u16*)alloc(BIGPK);
  u16* wih2p  = (u16*)alloc(BIGPK);
  u16* wih3p  = (u16*)alloc(BIGPK);
  u16* wfusep = (u16*)alloc(BIGPK);
  u16* wih1p  = (u16*)alloc((size_t)6 * 256 * 64 * 8 * 2);
  u16* wdecp  = (u16*)alloc((size_t)32 * 11 * 64 * 8 * 2);
  u16* seedp  = (u16*)alloc((size_t)NSEED * NB * NINP * 2);
  u16* h1h    = (u16*)alloc((size_t)NTT * HS * 2);   // 33.5 MB, write-once
  u16* h2h    = (u16*)alloc((size_t)NTT * HS * 2);   // 33.5 MB, write-once
  u16* h3h    = (u16*)alloc((size_t)NTT * HS * 2);   // 33.5 MB, write-once
  float* wftmp = (float*)alloc((size_t)NG * NH * 4); // 16.8 MB (no aliasing)
  float* b1s  = (float*)alloc((size_t)NG * 4);
  float* b1g  = (float*)alloc((size_t)NG * 4);
  float* b2   = (float*)alloc((size_t)NG * 4);
  float* b3   = (float*)alloc((size_t)NG * 4);
  float* bdecp = (float*)alloc((size_t)NOUTP * 4);
  int* flags  = (int*)alloc((size_t)NWG * 16 * 4);   // one flag per 64 B line

  // ---- prep ----
  pack_mat<<<dim3(2048), dim3(256), 0, stream>>>(Whh1, whh1p, 32);
  pack_mat<<<dim3(2048), dim3(256), 0, stream>>>(Whh2, whh2p, 32);
  pack_mat<<<dim3(2048), dim3(256), 0, stream>>>(Whh3, whh3p, 32);
  pack_mat<<<dim3(2048), dim3(256), 0, stream>>>(Wih2, wih2p, 32);
  pack_mat<<<dim3(2048), dim3(256), 0, stream>>>(Wih3, wih3p, 32);
  pack_wih1<<<dim3(384), dim3(256), 0, stream>>>(Wih1, wih1p);
  wfuse_kernel<<<dim3(4096, 4), dim3(256), 0, stream>>>(Wih1, Wdec, wftmp);
  pack_mat<<<dim3(2048), dim3(256), 0, stream>>>(wftmp, wfusep, 32);
  pack_wdec<<<dim3(88), dim3(256), 0, stream>>>(Wdec, wdecp);
  pack_seed<<<dim3(3072), dim3(256), 0, stream>>>(seed, seedp);
  prep_bias<<<dim3(16), dim3(256), 0, stream>>>(bih1, bhh1, bih2, bhh2, bih3, bhh3,
                                                Wih1, bdec, b1s, b1g, b2, b3, bdecp);
  // ---- recurrence ----
  lstm_main<<<dim3(NWG), dim3(256), 0, stream>>>(
      whh1p, whh2p, whh3p, wih2p, wih3p, wfusep, wih1p, seedp,
      h1h, h2h, h3h, b1s, b1g, b2, b3, flags);
  // ---- batched decoder ----
  dec_kernel<<<dim3(1408), dim3(256), 0, stream>>>(h3h, wdecp, bdecp, (float*)d_out);
}